// Round 5
// baseline (191.905 us; speedup 1.0000x reference)
//
#include <hip/hip_runtime.h>
#include <hip/hip_bf16.h>

// Problem constants
#define BATCH   256
#define NP      196
#define HIDDEN  1024
#define ATT     512
#define M_TOTAL (BATCH * NP)   // 50176 rows
#define BM 128
#define BN 128
#define NB_TILES (ATT / BN)       // 4
#define MT_TILES (M_TOTAL / BM)   // 392

typedef __attribute__((ext_vector_type(8))) short bf16x8v;  // 8 bf16 = 4 VGPR
typedef __attribute__((ext_vector_type(4))) float f32x4;

// f32 -> bf16 RNE (used only in K0 prep, cold path)
__device__ inline unsigned short f2bf(float x) {
    unsigned int u = __float_as_uint(x);
    u += 0x7fffu + ((u >> 16) & 1u);
    return (unsigned short)(u >> 16);
}

// packed f32 pair -> 2x bf16 in one uint via v_cvt_pk_bf16_f32
__device__ __forceinline__ unsigned int pk2bf(float lo, float hi) {
    unsigned int r;
    asm("v_cvt_pk_bf16_f32 %0, %1, %2" : "=v"(r) : "v"(lo), "v"(hi));
    return r;
}

__device__ inline float fast_tanh(float x) {
    float e = __expf(2.0f * x);
    return 1.0f - 2.0f / (e + 1.0f);
}

// async global->LDS, 16 bytes per lane. LDS dest must be wave-uniform base + lane*16.
__device__ __forceinline__ void glds16(const void* gsrc, void* ldst) {
    __builtin_amdgcn_global_load_lds(
        (const __attribute__((address_space(1))) unsigned int*)gsrc,
        (__attribute__((address_space(3))) unsigned int*)ldst,
        16, 0, 0);
}

// ---------------------------------------------------------------------------
// K0: W_cnn (f32 [1024][512]) -> bf16 tiled for K2's LDS B image:
//   Wt[nb 4][kt 32][chunk 4][colp 128][8k], with chunk-rotation:
//   slot (chunk, colp) holds logical col = (colp - chunk*4) & 127.
//   Per (nb,kt) a contiguous 8 KB image == the LDS B buffer (linear glds copy).
// ---------------------------------------------------------------------------
__global__ void k0_arrange(const float* __restrict__ Wc, unsigned short* __restrict__ Wt) {
    int g = blockIdx.x * 256 + threadIdx.x;   // 65536 slots of 8 bf16
    int nb    = g >> 14;
    int kt    = (g >> 9) & 31;
    int chunk = (g >> 7) & 3;
    int colp  = g & 127;
    int col   = nb * 128 + ((colp - chunk * 4) & 127);
    int kb    = kt * 32 + chunk * 8;
    unsigned short v[8];
#pragma unroll
    for (int j = 0; j < 8; ++j) v[j] = f2bf(Wc[(size_t)(kb + j) * ATT + col]);
    uint4 pk;
    pk.x = (unsigned int)v[0] | ((unsigned int)v[1] << 16);
    pk.y = (unsigned int)v[2] | ((unsigned int)v[3] << 16);
    pk.z = (unsigned int)v[4] | ((unsigned int)v[5] << 16);
    pk.w = (unsigned int)v[6] | ((unsigned int)v[7] << 16);
    *(uint4*)(Wt + (size_t)g * 8) = pk;
}

// ---------------------------------------------------------------------------
// K1: dec_out = decoder_out @ W_dec ; stw = st @ W_sen   (f32)
// ---------------------------------------------------------------------------
__global__ void k1_small(const float* __restrict__ dec_in, const float* __restrict__ st,
                         const float* __restrict__ Wdec,  const float* __restrict__ Wsen,
                         float* __restrict__ dec_out, float* __restrict__ stw) {
    const float* X = blockIdx.z ? st   : dec_in;
    const float* W = blockIdx.z ? Wsen : Wdec;
    float*       O = blockIdx.z ? stw  : dec_out;
    int ci = threadIdx.x & 31;
    int c0 = blockIdx.x * 128 + ci * 4;
    int b  = blockIdx.y * 8 + (threadIdx.x >> 5);
    const float* x = X + (size_t)b * HIDDEN;
    float4 acc = {0.f, 0.f, 0.f, 0.f};
    for (int k = 0; k < HIDDEN; k += 4) {
#pragma unroll
        for (int kk = 0; kk < 4; ++kk) {
            float4 w = *(const float4*)(W + (size_t)(k + kk) * ATT + c0);
            float a = x[k + kk];
            acc.x += a * w.x; acc.y += a * w.y; acc.z += a * w.z; acc.w += a * w.w;
        }
    }
    *(float4*)(O + (size_t)b * ATT + c0) = acc;
}

// ---------------------------------------------------------------------------
// K2: fused  zt_part[nb][r] = sum_{cols of nb} tanh((A@Wc)[r,a]+dec)*Watt[a]
// Tile 128x128, BK=32, 512 thr / 8 waves (4x2), wave = 32x64, acc[2][4] (32 AGPR).
// ALL staging via global_load_lds: A staged as f32 (16KB, XOR-swizzled image,
// inverse-swizzle on the global source), B bf16 (8KB, chunk-rotated image).
// THREE LDS buffers, staging 2 tiles ahead, counted s_waitcnt vmcnt(3) (never 0
// in the main loop), ONE barrier per K-tile. bf16 conversion at consume time
// via v_cvt_pk_bf16_f32. XCD-chunked swizzle: the 4 nb-blocks of each mt are
// adjacent on one XCD -> A strip L2 reuse.
// ---------------------------------------------------------------------------
__global__ void __launch_bounds__(512, 4)
k2_fused_gemm(const float* __restrict__ A, const unsigned short* __restrict__ Wt,
              const float* __restrict__ dec, const float* __restrict__ Watt,
              float* __restrict__ ztp) {
    // buffer q at lds + q*24576: [A f32 16KB][B bf16 8KB]
    __shared__ __align__(16) char lds[3 * 24576];   // 72 KB
    __shared__ float zred[256];                     //  1 KB

    const int tid = threadIdx.x;
    const int w  = tid >> 6;
    const int l  = tid & 63;
    const int lg = l >> 4, ll = l & 15;
    const int wr = w >> 1, wc = w & 1;       // wave grid 4 (rows) x 2 (cols)

    // XCD swizzle: 1568 blocks = 8 XCDs x 196; consecutive swz on one XCD
    // covers the 4 nb-blocks of an mt back-to-back.
    const int bid = (int)blockIdx.x;
    const int swz = (bid & 7) * 196 + (bid >> 3);
    const int mt = swz >> 2, nb = swz & 3;
    const int r0 = mt * BM;
    const int c0 = nb * BN;

    f32x4 acc[2][4];
#pragma unroll
    for (int m = 0; m < 2; ++m)
#pragma unroll
        for (int n = 0; n < 4; ++n) acc[m][n] = (f32x4){0.f, 0.f, 0.f, 0.f};

    char* ldsb = (char*)lds;

    // A stage: image row-major [row 128][8 slots of 16B], slot_phys = slot_log ^ (row&7).
    // dest byte (call c): c*8192 + tid*16  -> row = c*64 + tid>>3, slot_phys = tid&7.
    // source supplies the k-chunk slog = slot_phys ^ (row&7): 4 consecutive f32.
    const int row_d0 = (tid >> 3);
    const int row_d1 = 64 + (tid >> 3);
    const int sp = tid & 7;
    const float* asrc0 = A + (size_t)(r0 + row_d0) * HIDDEN + (sp ^ (row_d0 & 7)) * 4;
    const float* asrc1 = A + (size_t)(r0 + row_d1) * HIDDEN + (sp ^ (row_d1 & 7)) * 4;
    // B stage: linear copy of the 8KB (nb,kt) image.
    const char* bsrc = (const char*)Wt + (size_t)nb * 262144 + tid * 16;

#define STAGE(kt, q) do {                                                     \
    glds16(asrc0 + (kt) * 32, ldsb + (q) * 24576 + tid * 16);                 \
    glds16(asrc1 + (kt) * 32, ldsb + (q) * 24576 + 8192 + tid * 16);          \
    glds16(bsrc + (size_t)(kt) * 8192, ldsb + (q) * 24576 + 16384 + tid * 16);\
} while (0)

#define COMPUTE(q) do {                                                       \
    const char* Ab = ldsb + (q) * 24576;                                      \
    const char* Bb = Ab + 16384;                                              \
    bf16x8v af[2];                                                            \
    _Pragma("unroll")                                                         \
    for (int m = 0; m < 2; ++m) {                                             \
        int rl = wr * 32 + m * 16 + ll;                                       \
        int base = rl * 128;                                                  \
        f32x4 lo = *(const f32x4*)(Ab + base + (((lg * 2 + 0) ^ (rl & 7)) << 4)); \
        f32x4 hi = *(const f32x4*)(Ab + base + (((lg * 2 + 1) ^ (rl & 7)) << 4)); \
        uint4 u;                                                              \
        u.x = pk2bf(lo.x, lo.y); u.y = pk2bf(lo.z, lo.w);                     \
        u.z = pk2bf(hi.x, hi.y); u.w = pk2bf(hi.z, hi.w);                     \
        af[m] = *(bf16x8v*)&u;                                                \
    }                                                                         \
    bf16x8v bfr[4];                                                           \
    _Pragma("unroll")                                                         \
    for (int n = 0; n < 4; ++n) {                                             \
        int colp = ((wc * 64 + n * 16 + ll) + lg * 4) & 127;                  \
        bfr[n] = *(const bf16x8v*)(Bb + lg * 2048 + colp * 16);               \
    }                                                                         \
    __builtin_amdgcn_s_setprio(1);                                            \
    _Pragma("unroll")                                                         \
    for (int m = 0; m < 2; ++m)                                               \
        _Pragma("unroll")                                                     \
        for (int n = 0; n < 4; ++n)                                           \
            acc[m][n] = __builtin_amdgcn_mfma_f32_16x16x32_bf16(af[m], bfr[n], acc[m][n], 0, 0, 0); \
    __builtin_amdgcn_s_setprio(0);                                            \
} while (0)

#define WAIT3 asm volatile("s_waitcnt vmcnt(3) lgkmcnt(0)" ::: "memory")
#define BAR   __builtin_amdgcn_s_barrier()

    // Prologue: stage tiles 0,1 (6 glds in flight)
    STAGE(0, 0);
    STAGE(1, 1);

    // Main loop, unrolled x3 so buffer indices are compile-time constants.
    // iter t: wait stage(t) landed (vmcnt(3): stage(t+1)'s 3 stay in flight),
    // barrier, issue stage(t+2), compute tile t.
    for (int tb = 0; tb < 30; tb += 3) {
        WAIT3; BAR; STAGE(tb + 2, 2); COMPUTE(0);
        WAIT3; BAR; STAGE(tb + 3, 0); COMPUTE(1);
        WAIT3; BAR; STAGE(tb + 4, 1); COMPUTE(2);
    }
    // t=30 (buf 0): stage(31) already issued at t=29; nothing more to stage.
    WAIT3; BAR; COMPUTE(0);
    // t=31 (buf 1): drain.
    asm volatile("s_waitcnt vmcnt(0) lgkmcnt(0)" ::: "memory");
    BAR;
    COMPUTE(1);

#undef STAGE
#undef COMPUTE
#undef WAIT3
#undef BAR

    // Epilogue: tanh + dec add + Watt dot; reduce this wave's 64 cols per row.
    // C frag layout: row = lg*4 + j, col = ll (m89-verified).
    const int clocal = wc * 64 + ll;
    float watt[4];
#pragma unroll
    for (int n = 0; n < 4; ++n) watt[n] = Watt[c0 + clocal + n * 16];

#pragma unroll
    for (int m = 0; m < 2; ++m) {
#pragma unroll
        for (int j = 0; j < 4; ++j) {
            int rl = wr * 32 + m * 16 + lg * 4 + j;
            int rowg = r0 + rl;
            int b = rowg / NP;
            const float* db = dec + (size_t)b * ATT + c0;
            float s = 0.f;
#pragma unroll
            for (int n = 0; n < 4; ++n)
                s += fast_tanh(acc[m][n][j] + db[clocal + n * 16]) * watt[n];
            s += __shfl_xor(s, 1);
            s += __shfl_xor(s, 2);
            s += __shfl_xor(s, 4);
            s += __shfl_xor(s, 8);
            if (ll == 0) zred[rl * 2 + wc] = s;
        }
    }
    __syncthreads();
    if (tid < 128) {
        float t = zred[tid * 2] + zred[tid * 2 + 1];
        ztp[(size_t)nb * M_TOTAL + r0 + tid] = t;
    }
}

// ---------------------------------------------------------------------------
// K3: per-b: out = tanh(dec+stw)@Watt ; alpha = softmax(zt) ; beta.
// zt = sum of 4 N-block partials.
// ---------------------------------------------------------------------------
__global__ void k3_softmax(const float* __restrict__ dec, const float* __restrict__ stw,
                           const float* __restrict__ Watt, const float* __restrict__ ztp,
                           float* __restrict__ out, float* __restrict__ beta_ws) {
    int b = blockIdx.x;
    int t = threadIdx.x;
    __shared__ float red[256];

    float p = 0.f;
#pragma unroll
    for (int c = t; c < ATT; c += 256)
        p += fast_tanh(dec[(size_t)b * ATT + c] + stw[(size_t)b * ATT + c]) * Watt[c];
    red[t] = p;
    __syncthreads();
    for (int s = 128; s > 0; s >>= 1) { if (t < s) red[t] += red[t + s]; __syncthreads(); }
    float outv = red[0];
    __syncthreads();

    float z = -1e30f;
    if (t < NP) {
        z = ztp[b * NP + t] + ztp[M_TOTAL + b * NP + t]
          + ztp[2 * M_TOTAL + b * NP + t] + ztp[3 * M_TOTAL + b * NP + t];
    }
    red[t] = z;
    __syncthreads();
    for (int s = 128; s > 0; s >>= 1) { if (t < s) red[t] = fmaxf(red[t], red[t + s]); __syncthreads(); }
    float m1 = red[0];
    __syncthreads();

    float e = (t < NP) ? __expf(z - m1) : 0.f;
    red[t] = e;
    __syncthreads();
    for (int s = 128; s > 0; s >>= 1) { if (t < s) red[t] += red[t + s]; __syncthreads(); }
    float s1 = red[0];

    if (t < NP) out[b * NP + t] = e / s1;                       // alpha_t

    if (t == 0) {
        float m2 = fmaxf(m1, outv);
        float s2 = s1 * __expf(m1 - m2) + __expf(outv - m2);
        float beta = __expf(outv - m2) / s2;
        out[M_TOTAL + b] = beta;                                 // beta_t
        beta_ws[b] = beta;
    }
}

// ---------------------------------------------------------------------------
// K4: ct partials. grid (4 p-quarters, 256 b), block 256 (thread = 4 h).
// ---------------------------------------------------------------------------
__global__ void k4_ct(const float* __restrict__ spatial, const float* __restrict__ alpha,
                      float* __restrict__ ctp) {
    int q = blockIdx.x;
    int b = blockIdx.y;
    int t = threadIdx.x;
    __shared__ float al[49];
    if (t < 49) al[t] = alpha[b * NP + q * 49 + t];
    __syncthreads();
    const float* sp = spatial + (size_t)b * NP * HIDDEN + (size_t)q * 49 * HIDDEN + t * 4;
    float4 acc = {0.f, 0.f, 0.f, 0.f};
#pragma unroll 7
    for (int p = 0; p < 49; ++p) {
        float4 v = *(const float4*)(sp + (size_t)p * HIDDEN);
        float a = al[p];
        acc.x += a * v.x; acc.y += a * v.y; acc.z += a * v.z; acc.w += a * v.w;
    }
    *(float4*)(ctp + ((size_t)q * BATCH + b) * HIDDEN + t * 4) = acc;
}

// ---------------------------------------------------------------------------
// K5: c_hat = beta*st + (1-beta)*ct  (sums the 4 ct partials)
// ---------------------------------------------------------------------------
__global__ void k5_chat(const float* __restrict__ st, const float* __restrict__ ctp,
                        const float* __restrict__ beta, float* __restrict__ chat) {
    int g = blockIdx.x * 256 + threadIdx.x;
    int b = g >> 8;
    int h0 = (g & 255) * 4;
    float be = beta[b];
    float4 s = *(const float4*)(st + (size_t)b * HIDDEN + h0);
    float4 c = {0.f, 0.f, 0.f, 0.f};
#pragma unroll
    for (int q = 0; q < 4; ++q) {
        float4 v = *(const float4*)(ctp + ((size_t)q * BATCH + b) * HIDDEN + h0);
        c.x += v.x; c.y += v.y; c.z += v.z; c.w += v.w;
    }
    float4 o;
    o.x = be * s.x + (1.f - be) * c.x;
    o.y = be * s.y + (1.f - be) * c.y;
    o.z = be * s.z + (1.f - be) * c.z;
    o.w = be * s.w + (1.f - be) * c.w;
    *(float4*)(chat + (size_t)b * HIDDEN + h0) = o;
}

// ---------------------------------------------------------------------------
extern "C" void kernel_launch(void* const* d_in, const int* in_sizes, int n_in,
                              void* d_out, int out_size, void* d_ws, size_t ws_size,
                              hipStream_t stream) {
    const float* spatial = (const float*)d_in[0];   // (256,196,1024)
    const float* decoder = (const float*)d_in[1];   // (256,1024)
    const float* st      = (const float*)d_in[2];   // (256,1024)
    const float* Wcnn    = (const float*)d_in[3];   // (1024,512)
    const float* Wdec    = (const float*)d_in[4];   // (1024,512)
    const float* Wsen    = (const float*)d_in[5];   // (1024,512)
    const float* Watt    = (const float*)d_in[6];   // (512,1)
    float* out = (float*)d_out;   // alpha[50176] | beta[256] | c_hat[262144]

    char* ws = (char*)d_ws;
    unsigned short* Wt = (unsigned short*)(ws + 0);   // 1 MB tiled bf16 W_cnn
    float* ztp  = (float*)(ws + 1048576);             // 4 x 50176 partials (802816 B)
    float* dec  = (float*)(ws + 1851392);             // 256x512
    float* stw  = (float*)(ws + 2375680);             // 256x512
    float* beta = (float*)(ws + 2899968);             // 256
    float* ctp  = (float*)(ws + 2901504);             // 4x256x1024 partials (4 MB)

    k0_arrange<<<256, 256, 0, stream>>>(Wcnn, Wt);
    k1_small<<<dim3(4, 32, 2), 256, 0, stream>>>(decoder, st, Wdec, Wsen, dec, stw);
    k2_fused_gemm<<<MT_TILES * NB_TILES, 512, 0, stream>>>(spatial, Wt, dec, Watt, ztp);
    k3_softmax<<<256, 256, 0, stream>>>(dec, stw, Watt, ztp, out, beta);
    k4_ct<<<dim3(4, 256), 256, 0, stream>>>(spatial, out, ctp);
    k5_chat<<<256, 256, 0, stream>>>(st, ctp, beta, out + M_TOTAL + BATCH);
}